// Round 1
// baseline (194.068 us; speedup 1.0000x reference)
//
#include <hip/hip_runtime.h>
#include <hip/hip_bf16.h>
#include <cstdint>

typedef __attribute__((ext_vector_type(8))) short short8;
typedef __attribute__((ext_vector_type(4))) float floatx4;

__device__ __forceinline__ float bf2f(unsigned short u) {
  unsigned int x = ((unsigned int)u) << 16;
  return __builtin_bit_cast(float, x);
}
__device__ __forceinline__ unsigned short f2bf(float f) {
  unsigned int x = __builtin_bit_cast(unsigned int, f);
  x += 0x7fffu + ((x >> 16) & 1u);   // RNE (inputs are sane, no NaN handling)
  return (unsigned short)(x >> 16);
}

__device__ __forceinline__ void gload_lds16(const void* g, void* l) {
  __builtin_amdgcn_global_load_lds(
      (const __attribute__((address_space(1))) void*)g,
      (__attribute__((address_space(3))) void*)l, 16, 0, 0);
}

// ---------------- converts ----------------

__global__ __launch_bounds__(256) void cvtx_kernel(const float* __restrict__ x,
                                                   unsigned short* __restrict__ xb) {
  int i = blockIdx.x * 256 + threadIdx.x;  // chunk of 8 elems, grid sized exactly
  const float4* xf = (const float4*)x;
  float4 a = xf[i * 2], b = xf[i * 2 + 1];
  short8 o;
  o[0] = (short)f2bf(a.x); o[1] = (short)f2bf(a.y);
  o[2] = (short)f2bf(a.z); o[3] = (short)f2bf(a.w);
  o[4] = (short)f2bf(b.x); o[5] = (short)f2bf(b.y);
  o[6] = (short)f2bf(b.z); o[7] = (short)f2bf(b.w);
  ((short8*)xb)[i] = o;
}

// W [1024(d_in)][1024(d_out)] f32 -> Wt [d_out][d_in] bf16 (transposed)
__global__ __launch_bounds__(256) void wt_kernel(const float* __restrict__ Wq,
                                                 const float* __restrict__ Wk,
                                                 const float* __restrict__ Wv,
                                                 unsigned short* __restrict__ Wt) {
  int z = blockIdx.z;
  const float* W = z == 0 ? Wq : (z == 1 ? Wk : Wv);
  unsigned short* O = Wt + (size_t)z * 1024 * 1024;
  __shared__ float tile[64][65];
  int c0 = blockIdx.x * 64;  // d_out block (cols of W)
  int r0 = blockIdx.y * 64;  // d_in block (rows of W)
  int tid = threadIdx.x;
#pragma unroll
  for (int i = 0; i < 4; ++i) {
    int c = tid + i * 256; int rr = c >> 4, q = c & 15;
    float4 v = *(const float4*)&W[(size_t)(r0 + rr) * 1024 + c0 + q * 4];
    tile[rr][q * 4 + 0] = v.x; tile[rr][q * 4 + 1] = v.y;
    tile[rr][q * 4 + 2] = v.z; tile[rr][q * 4 + 3] = v.w;
  }
  __syncthreads();
#pragma unroll
  for (int i = 0; i < 2; ++i) {
    int c = tid + i * 256; int oc = c >> 3, q = c & 7;
    short8 o;
#pragma unroll
    for (int j = 0; j < 8; ++j) o[j] = (short)f2bf(tile[q * 8 + j][oc]);
    *(short8*)&O[(size_t)(c0 + oc) * 1024 + r0 + q * 8] = o;
  }
}

// V [2048][1024] bf16 -> Vt [1024][2048] bf16, per batch (blockIdx.z)
__global__ __launch_bounds__(256) void vt_kernel(const unsigned short* __restrict__ V,
                                                 unsigned short* __restrict__ Vt) {
  int b = blockIdx.z;
  const unsigned short* Vb = V + (size_t)b * 2048 * 1024;
  unsigned short* Vtb = Vt + (size_t)b * 1024 * 2048;
  __shared__ unsigned short tile[64][72];
  int t0 = blockIdx.x * 64;  // T block
  int e0 = blockIdx.y * 64;  // E block
  int tid = threadIdx.x;
#pragma unroll
  for (int i = 0; i < 2; ++i) {
    int c = tid + i * 256; int rr = c >> 3, q = c & 7;
    short8 s = *(const short8*)&Vb[(size_t)(t0 + rr) * 1024 + e0 + q * 8];
#pragma unroll
    for (int j = 0; j < 8; ++j) tile[rr][q * 8 + j] = (unsigned short)s[j];
  }
  __syncthreads();
#pragma unroll
  for (int i = 0; i < 2; ++i) {
    int c = tid + i * 256; int er = c >> 3, q = c & 7;
    short8 o;
#pragma unroll
    for (int j = 0; j < 8; ++j) o[j] = (short)tile[q * 8 + j][er];
    *(short8*)&Vtb[(size_t)(e0 + er) * 2048 + t0 + q * 8] = o;
  }
}

// ---------------- TN GEMM core (m97 structure) ----------------
// C[M,N] = A[M,K] * B[N,K]^T, bf16 in, f32 acc. 128x128 tile, BK=32, 4 waves.

template <bool OUT_BF16>
__device__ __forceinline__ void gemm_tn_core(const unsigned short* __restrict__ A,
                                             const unsigned short* __restrict__ B,
                                             void* __restrict__ C,
                                             int lda, int ldb, int ldc,
                                             int m0, int n0, int kTiles) {
  __shared__ __align__(16) unsigned short Asm[2][128 * 32];
  __shared__ __align__(16) unsigned short Bsm[2][128 * 32];
  const int tid = threadIdx.x;
  const int lane = tid & 63;
  const int wave = tid >> 6;
  const int wrow = (wave >> 1) * 64;
  const int wcol = (wave & 1) * 64;
  const int r15 = lane & 15;
  const int kg = (lane >> 4) * 8;

  floatx4 acc[4][4] = {};

  const unsigned short* Ag = A + (size_t)m0 * lda;
  const unsigned short* Bg = B + (size_t)n0 * ldb;

  auto stage = [&](int buf, int kt) {
    int k0 = kt * 32;
#pragma unroll
    for (int i = 0; i < 2; ++i) {
      int c = tid + i * 256;
      gload_lds16(Ag + (size_t)(c >> 2) * lda + k0 + (c & 3) * 8, &Asm[buf][c * 8]);
    }
#pragma unroll
    for (int i = 0; i < 2; ++i) {
      int c = tid + i * 256;
      gload_lds16(Bg + (size_t)(c >> 2) * ldb + k0 + (c & 3) * 8, &Bsm[buf][c * 8]);
    }
  };

  stage(0, 0);
  for (int kt = 0; kt < kTiles; ++kt) {
    int cur = kt & 1;
    __syncthreads();  // drains vmcnt -> buf[cur] staged; prior ds_reads done
    if (kt + 1 < kTiles) stage(cur ^ 1, kt + 1);
    const unsigned short* As = Asm[cur];
    const unsigned short* Bs = Bsm[cur];
    short8 af[4], bfr[4];
#pragma unroll
    for (int m = 0; m < 4; ++m)
      af[m] = *(const short8*)&As[(wrow + m * 16 + r15) * 32 + kg];
#pragma unroll
    for (int n = 0; n < 4; ++n)
      bfr[n] = *(const short8*)&Bs[(wcol + n * 16 + r15) * 32 + kg];
#pragma unroll
    for (int m = 0; m < 4; ++m)
#pragma unroll
      for (int n = 0; n < 4; ++n)
        acc[m][n] = __builtin_amdgcn_mfma_f32_16x16x32_bf16(af[m], bfr[n], acc[m][n], 0, 0, 0);
  }

  const int rq = (lane >> 4) * 4;
#pragma unroll
  for (int m = 0; m < 4; ++m) {
#pragma unroll
    for (int n = 0; n < 4; ++n) {
      int gc = n0 + wcol + n * 16 + r15;
#pragma unroll
      for (int r = 0; r < 4; ++r) {
        int gr = m0 + wrow + m * 16 + rq + r;
        if (OUT_BF16)
          ((unsigned short*)C)[(size_t)gr * ldc + gc] = f2bf(acc[m][n][r]);
        else
          ((float*)C)[(size_t)gr * ldc + gc] = acc[m][n][r];
      }
    }
  }
}

// QKV: z selects Wq/Wk/Wv; X [8192,1024] @ Wt[z] [1024(n),1024(k)] -> QKV[z] bf16
__global__ __launch_bounds__(256) void qkv_kernel(const unsigned short* __restrict__ Xb,
                                                  const unsigned short* __restrict__ Wt,
                                                  unsigned short* __restrict__ QKV) {
  gemm_tn_core<true>(Xb, Wt + (size_t)blockIdx.z * 1024 * 1024,
                     QKV + (size_t)blockIdx.z * 8192 * 1024,
                     1024, 1024, 1024, blockIdx.x * 128, blockIdx.y * 128, 32);
}

// S: triangular grid over (qb, kb<=qb); S[b] [2048,2048] bf16 (upper-tri of diag blocks = garbage, ignored)
__global__ __launch_bounds__(256) void s_kernel(const unsigned short* __restrict__ Q,
                                                const unsigned short* __restrict__ K,
                                                unsigned short* __restrict__ S) {
  int t = blockIdx.x;
  int qb = (int)((sqrtf(8.f * (float)t + 1.f) - 1.f) * 0.5f);
  while ((qb + 1) * (qb + 2) / 2 <= t) ++qb;
  while (qb * (qb + 1) / 2 > t) --qb;
  int kb = t - qb * (qb + 1) / 2;
  size_t b = blockIdx.y;
  gemm_tn_core<true>(Q + b * 2048 * 1024, K + b * 2048 * 1024, S + b * 2048 * 2048,
                     1024, 1024, 2048, qb * 128, kb * 128, 32);
}

// PV: O[b] [2048,1024] f32 = P[b] @ V[b]; K-extent limited to (qb+1)*128 (causal)
__global__ __launch_bounds__(256) void pv_kernel(const unsigned short* __restrict__ P,
                                                 const unsigned short* __restrict__ Vt,
                                                 float* __restrict__ O) {
  int qb = blockIdx.x;
  size_t b = blockIdx.z;
  gemm_tn_core<false>(P + b * 2048 * 2048, Vt + b * 1024 * 2048, O + b * 2048 * 1024,
                      2048, 2048, 1024, qb * 128, blockIdx.y * 128, (qb + 1) * 4);
}

// ---------------- softmax (in-place on bf16 S) ----------------
// One 256-thread block per row. Reads k<=r, writes normalized p for k<=r and
// ZEROS for r<k<padEnd (so PV can read rectangular causal tiles).
__global__ __launch_bounds__(256) void softmax_kernel(unsigned short* __restrict__ S) {
  const int r = blockIdx.x;
  const int b = blockIdx.y;
  unsigned short* row = S + ((size_t)b * 2048 + r) * 2048;
  const int len = r + 1;
  const int padEnd = ((r >> 7) + 1) << 7;
  const int tid = threadIdx.x;
  const int base = tid * 8;
  const float scale = 0.03125f;  // 1/sqrt(1024)

  float v[8];
  float mymax = -1e30f;
  if (base < len) {
    short8 s = *(const short8*)(row + base);
#pragma unroll
    for (int j = 0; j < 8; ++j) {
      float f = (base + j < len) ? bf2f((unsigned short)s[j]) : -1e30f;
      v[j] = f;
      mymax = fmaxf(mymax, f);
    }
  } else {
#pragma unroll
    for (int j = 0; j < 8; ++j) v[j] = -1e30f;
  }

  __shared__ float redm[4], reds[4];
  const int wave = tid >> 6, lane = tid & 63;
#pragma unroll
  for (int off = 32; off > 0; off >>= 1) mymax = fmaxf(mymax, __shfl_xor(mymax, off, 64));
  if (lane == 0) redm[wave] = mymax;
  __syncthreads();
  float m = fmaxf(fmaxf(redm[0], redm[1]), fmaxf(redm[2], redm[3])) * scale;

  float p[8];
  float mysum = 0.f;
#pragma unroll
  for (int j = 0; j < 8; ++j) {
    float e = (base + j < len) ? __expf(v[j] * scale - m) : 0.f;
    p[j] = e;
    mysum += e;
  }
#pragma unroll
  for (int off = 32; off > 0; off >>= 1) mysum += __shfl_xor(mysum, off, 64);
  if (lane == 0) reds[wave] = mysum;
  __syncthreads();
  float inv = 1.f / (reds[0] + reds[1] + reds[2] + reds[3]);

  if (base < padEnd) {
    short8 o;
#pragma unroll
    for (int j = 0; j < 8; ++j) o[j] = (short)f2bf(p[j] * inv);
    *(short8*)(row + base) = o;
  }
}

// ---------------- launch ----------------

extern "C" void kernel_launch(void* const* d_in, const int* in_sizes, int n_in,
                              void* d_out, int out_size, void* d_ws, size_t ws_size,
                              hipStream_t stream) {
  const float* x  = (const float*)d_in[0];
  const float* Wq = (const float*)d_in[1];
  const float* Wk = (const float*)d_in[2];
  const float* Wv = (const float*)d_in[3];
  float* out = (float*)d_out;

  // workspace layout (bf16 elems): total ~118 MB
  unsigned short* Xb  = (unsigned short*)d_ws;                  // 8192*1024        (16 MB)
  unsigned short* Wt  = Xb + (size_t)8192 * 1024;               // 3*1024*1024      (6 MB)
  unsigned short* QKV = Wt + (size_t)3 * 1024 * 1024;           // 3*8192*1024      (48 MB)
  unsigned short* Vt  = QKV + (size_t)3 * 8192 * 1024;          // 4*1024*2048      (16 MB)
  unsigned short* S   = Vt + (size_t)4 * 1024 * 2048;           // 4*2048*2048      (32 MB)

  const unsigned short* Qp = QKV;
  const unsigned short* Kp = QKV + (size_t)8192 * 1024;
  const unsigned short* Vp = QKV + (size_t)2 * 8192 * 1024;

  hipLaunchKernelGGL(cvtx_kernel, dim3(4096), dim3(256), 0, stream, x, Xb);
  hipLaunchKernelGGL(wt_kernel, dim3(16, 16, 3), dim3(256), 0, stream, Wq, Wk, Wv, Wt);
  hipLaunchKernelGGL(qkv_kernel, dim3(64, 8, 3), dim3(256), 0, stream, Xb, Wt, QKV);
  hipLaunchKernelGGL(vt_kernel, dim3(32, 16, 4), dim3(256), 0, stream, Vp, Vt);
  hipLaunchKernelGGL(s_kernel, dim3(136, 4), dim3(256), 0, stream, Qp, Kp, S);
  hipLaunchKernelGGL(softmax_kernel, dim3(2048, 4), dim3(256), 0, stream, S);
  hipLaunchKernelGGL(pv_kernel, dim3(16, 8, 4), dim3(256), 0, stream, S, Vt, out);
}

// Round 2
// 188.693 us; speedup vs baseline: 1.0285x; 1.0285x over previous
//
#include <hip/hip_runtime.h>
#include <hip/hip_bf16.h>
#include <cstdint>

typedef __attribute__((ext_vector_type(8))) short short8;
typedef __attribute__((ext_vector_type(4))) float floatx4;
typedef unsigned short ushort;

__device__ __forceinline__ float bf2f(ushort u) {
  unsigned int x = ((unsigned int)u) << 16;
  return __builtin_bit_cast(float, x);
}
__device__ __forceinline__ ushort f2bf(float f) {
  unsigned int x = __builtin_bit_cast(unsigned int, f);
  x += 0x7fffu + ((x >> 16) & 1u);   // RNE
  return (ushort)(x >> 16);
}

__device__ __forceinline__ void gload_lds16(const void* g, void* l) {
  __builtin_amdgcn_global_load_lds(
      (const __attribute__((address_space(1))) void*)g,
      (__attribute__((address_space(3))) void*)l, 16, 0, 0);
}

// ---------------- converts ----------------

__global__ __launch_bounds__(256) void cvtx_kernel(const float* __restrict__ x,
                                                   ushort* __restrict__ xb) {
  int i = blockIdx.x * 256 + threadIdx.x;
  const float4* xf = (const float4*)x;
  float4 a = xf[i * 2], b = xf[i * 2 + 1];
  short8 o;
  o[0] = (short)f2bf(a.x); o[1] = (short)f2bf(a.y);
  o[2] = (short)f2bf(a.z); o[3] = (short)f2bf(a.w);
  o[4] = (short)f2bf(b.x); o[5] = (short)f2bf(b.y);
  o[6] = (short)f2bf(b.z); o[7] = (short)f2bf(b.w);
  ((short8*)xb)[i] = o;
}

// W [1024(d_in)][1024(d_out)] f32 -> Wt [d_out][d_in] bf16 (transposed)
__global__ __launch_bounds__(256) void wt_kernel(const float* __restrict__ Wq,
                                                 const float* __restrict__ Wk,
                                                 const float* __restrict__ Wv,
                                                 ushort* __restrict__ Wt) {
  int z = blockIdx.z;
  const float* W = z == 0 ? Wq : (z == 1 ? Wk : Wv);
  ushort* O = Wt + (size_t)z * 1024 * 1024;
  __shared__ float tile[64][65];
  int c0 = blockIdx.x * 64;
  int r0 = blockIdx.y * 64;
  int tid = threadIdx.x;
#pragma unroll
  for (int i = 0; i < 4; ++i) {
    int c = tid + i * 256; int rr = c >> 4, q = c & 15;
    float4 v = *(const float4*)&W[(size_t)(r0 + rr) * 1024 + c0 + q * 4];
    tile[rr][q * 4 + 0] = v.x; tile[rr][q * 4 + 1] = v.y;
    tile[rr][q * 4 + 2] = v.z; tile[rr][q * 4 + 3] = v.w;
  }
  __syncthreads();
#pragma unroll
  for (int i = 0; i < 2; ++i) {
    int c = tid + i * 256; int oc = c >> 3, q = c & 7;
    short8 o;
#pragma unroll
    for (int j = 0; j < 8; ++j) o[j] = (short)f2bf(tile[q * 8 + j][oc]);
    *(short8*)&O[(size_t)(c0 + oc) * 1024 + r0 + q * 8] = o;
  }
}

// V [2048][1024] bf16 -> Vt [1024][2048] bf16, per batch
__global__ __launch_bounds__(256) void vt_kernel(const ushort* __restrict__ V,
                                                 ushort* __restrict__ Vt) {
  int b = blockIdx.z;
  const ushort* Vb = V + (size_t)b * 2048 * 1024;
  ushort* Vtb = Vt + (size_t)b * 1024 * 2048;
  __shared__ ushort tile[64][72];
  int t0 = blockIdx.x * 64;
  int e0 = blockIdx.y * 64;
  int tid = threadIdx.x;
#pragma unroll
  for (int i = 0; i < 2; ++i) {
    int c = tid + i * 256; int rr = c >> 3, q = c & 7;
    short8 s = *(const short8*)&Vb[(size_t)(t0 + rr) * 1024 + e0 + q * 8];
#pragma unroll
    for (int j = 0; j < 8; ++j) tile[rr][q * 8 + j] = (ushort)s[j];
  }
  __syncthreads();
#pragma unroll
  for (int i = 0; i < 2; ++i) {
    int c = tid + i * 256; int er = c >> 3, q = c & 7;
    short8 o;
#pragma unroll
    for (int j = 0; j < 8; ++j) o[j] = (short)tile[q * 8 + j][er];
    *(short8*)&Vtb[(size_t)(e0 + er) * 2048 + t0 + q * 8] = o;
  }
}

// ---------------- 8-phase 256x256 GEMM for fused QKV ----------------
// C[8192,3072] = X[8192,1024] * WtAll[3072,1024]^T, output z-split into QKV.
// 512 threads (8 waves, 2M x 4N), BK=64, LDS half-tiles [256 rows][32 k],
// swizzle mask ((row>>1)&3)<<4, counted vmcnt(4) every 2 phases.

__global__ __launch_bounds__(512, 2) void qkv8_kernel(const ushort* __restrict__ A,
                                                      const ushort* __restrict__ Bm,
                                                      ushort* __restrict__ QKV) {
  // [buf][mat 0=A,1=B][kh][256*32 elems]
  __shared__ __align__(16) ushort lds[2][2][2][8192];

  const int tid = threadIdx.x;
  const int lane = tid & 63;
  const int wave = tid >> 6;
  const int wm = wave >> 2;   // 0..1 -> row half
  const int wn = wave & 3;    // 0..3 -> 64-col slice
  const int r15 = lane & 15;
  const int kg = lane >> 4;   // 0..3

  // XCD-bijective swizzle (nwg = 384, 384 % 8 == 0)
  const int nwgx = 32, nwgy = 12;
  int orig = blockIdx.y * nwgx + blockIdx.x;
  int swz = (orig & 7) * ((nwgx * nwgy) >> 3) + (orig >> 3);
  int by = swz % nwgy;
  int bx = swz / nwgy;
  const int m0 = bx * 256;
  const int n0 = by * 256;

  const ushort* Ag = A + (size_t)m0 * 1024;
  const ushort* Bg = Bm + (size_t)n0 * 1024;

  const int NKT = 16;  // 1024 / 64

  floatx4 acc[8][4] = {};

  // stage stream: idx = kt*4 + hh; hh: 0=A kh0, 1=B kh0, 2=A kh1, 3=B kh1
  auto stage = [&](int sidx) {
    int kt = sidx >> 2, hh = sidx & 3;
    int mat = hh & 1, kh = hh >> 1;
    ushort* dst = &lds[kt & 1][mat][kh][0];
    const ushort* src = mat ? Bg : Ag;
    int kbase = kt * 64 + kh * 32;
#pragma unroll
    for (int i = 0; i < 2; ++i) {
      int t = tid + i * 512;
      int d = t * 16;                           // linear dest byte
      int L = d ^ (((d >> 7) & 3) << 4);        // inverse-swizzled logical byte
      int row = L >> 6;
      int colE = (L & 63) >> 1;
      gload_lds16(src + (size_t)row * 1024 + kbase + colE, dst + t * 8);
    }
  };

  // swizzled ds_read of one 16x... fragment (8 bf16 = 16B)
  auto ldA = [&](int buf, int ks, int m) -> short8 {
    int row = wm * 128 + m * 16 + r15;
    int L = row * 64 + kg * 16;
    int P = L ^ (((row >> 1) & 3) << 4);
    return *(const short8*)((const char*)&lds[buf][0][ks][0] + P);
  };
  auto ldB = [&](int buf, int ks, int n) -> short8 {
    int row = wn * 64 + n * 16 + r15;
    int L = row * 64 + kg * 16;
    int P = L ^ (((row >> 1) & 3) << 4);
    return *(const short8*)((const char*)&lds[buf][1][ks][0] + P);
  };

  // prologue: 6 half-tiles in flight; first 2 landed before phase 0
  for (int s = 0; s < 6; ++s) stage(s);
  asm volatile("s_waitcnt vmcnt(8)" ::: "memory");
  __builtin_amdgcn_s_barrier();

  short8 bfrag[4];
  int sidx = 6;
  for (int kt = 0; kt < NKT; ++kt) {
    int cur = kt & 1;
#pragma unroll
    for (int q = 0; q < 4; ++q) {
      const int ks = q >> 1;
      const int msub = (q & 1) * 4;
      short8 afrag[4];
      if ((q & 1) == 0) {
#pragma unroll
        for (int n = 0; n < 4; ++n) bfrag[n] = ldB(cur, ks, n);
      }
#pragma unroll
      for (int m = 0; m < 4; ++m) afrag[m] = ldA(cur, ks, msub + m);
      if (sidx < NKT * 4) stage(sidx);
      ++sidx;
      if (q & 1) asm volatile("s_waitcnt vmcnt(4)" ::: "memory");
      __builtin_amdgcn_s_barrier();
      asm volatile("s_waitcnt lgkmcnt(0)" ::: "memory");
      __builtin_amdgcn_sched_barrier(0);
      __builtin_amdgcn_s_setprio(1);
#pragma unroll
      for (int m = 0; m < 4; ++m)
#pragma unroll
        for (int n = 0; n < 4; ++n)
          acc[msub + m][n] =
              __builtin_amdgcn_mfma_f32_16x16x32_bf16(afrag[m], bfrag[n], acc[msub + m][n], 0, 0, 0);
      __builtin_amdgcn_s_setprio(0);
      __builtin_amdgcn_s_barrier();
    }
  }

  // epilogue: z-split store (each 256-col block lies inside one z)
  ushort* Cz = QKV + (size_t)(n0 >> 10) * 8192 * 1024;
  const int cb = n0 & 1023;
  const int rq = kg * 4;
#pragma unroll
  for (int m = 0; m < 8; ++m) {
#pragma unroll
    for (int n = 0; n < 4; ++n) {
      int gc = cb + wn * 64 + n * 16 + r15;
#pragma unroll
      for (int r = 0; r < 4; ++r) {
        int gr = m0 + wm * 128 + m * 16 + rq + r;
        Cz[(size_t)gr * 1024 + gc] = f2bf(acc[m][n][r]);
      }
    }
  }
}

// ---------------- TN GEMM core (m97 structure) for S and PV ----------------

template <bool OUT_BF16>
__device__ __forceinline__ void gemm_tn_core(const ushort* __restrict__ A,
                                             const ushort* __restrict__ B,
                                             void* __restrict__ C,
                                             int lda, int ldb, int ldc,
                                             int m0, int n0, int kTiles) {
  __shared__ __align__(16) ushort Asm[2][128 * 32];
  __shared__ __align__(16) ushort Bsm[2][128 * 32];
  const int tid = threadIdx.x;
  const int lane = tid & 63;
  const int wave = tid >> 6;
  const int wrow = (wave >> 1) * 64;
  const int wcol = (wave & 1) * 64;
  const int r15 = lane & 15;
  const int kg = (lane >> 4) * 8;

  floatx4 acc[4][4] = {};

  const ushort* Ag = A + (size_t)m0 * lda;
  const ushort* Bg = B + (size_t)n0 * ldb;

  auto stage = [&](int buf, int kt) {
    int k0 = kt * 32;
#pragma unroll
    for (int i = 0; i < 2; ++i) {
      int c = tid + i * 256;
      gload_lds16(Ag + (size_t)(c >> 2) * lda + k0 + (c & 3) * 8, &Asm[buf][c * 8]);
    }
#pragma unroll
    for (int i = 0; i < 2; ++i) {
      int c = tid + i * 256;
      gload_lds16(Bg + (size_t)(c >> 2) * ldb + k0 + (c & 3) * 8, &Bsm[buf][c * 8]);
    }
  };

  stage(0, 0);
  for (int kt = 0; kt < kTiles; ++kt) {
    int cur = kt & 1;
    __syncthreads();
    if (kt + 1 < kTiles) stage(cur ^ 1, kt + 1);
    const ushort* As = Asm[cur];
    const ushort* Bs = Bsm[cur];
    short8 af[4], bfr[4];
#pragma unroll
    for (int m = 0; m < 4; ++m)
      af[m] = *(const short8*)&As[(wrow + m * 16 + r15) * 32 + kg];
#pragma unroll
    for (int n = 0; n < 4; ++n)
      bfr[n] = *(const short8*)&Bs[(wcol + n * 16 + r15) * 32 + kg];
#pragma unroll
    for (int m = 0; m < 4; ++m)
#pragma unroll
      for (int n = 0; n < 4; ++n)
        acc[m][n] = __builtin_amdgcn_mfma_f32_16x16x32_bf16(af[m], bfr[n], acc[m][n], 0, 0, 0);
  }

  const int rq = (lane >> 4) * 4;
#pragma unroll
  for (int m = 0; m < 4; ++m) {
#pragma unroll
    for (int n = 0; n < 4; ++n) {
      int gc = n0 + wcol + n * 16 + r15;
#pragma unroll
      for (int r = 0; r < 4; ++r) {
        int gr = m0 + wrow + m * 16 + rq + r;
        if (OUT_BF16)
          ((ushort*)C)[(size_t)gr * ldc + gc] = f2bf(acc[m][n][r]);
        else
          ((float*)C)[(size_t)gr * ldc + gc] = acc[m][n][r];
      }
    }
  }
}

// S: triangular grid over (qb, kb<=qb)
__global__ __launch_bounds__(256) void s_kernel(const ushort* __restrict__ Q,
                                                const ushort* __restrict__ K,
                                                ushort* __restrict__ S) {
  int t = blockIdx.x;
  int qb = (int)((sqrtf(8.f * (float)t + 1.f) - 1.f) * 0.5f);
  while ((qb + 1) * (qb + 2) / 2 <= t) ++qb;
  while (qb * (qb + 1) / 2 > t) --qb;
  int kb = t - qb * (qb + 1) / 2;
  size_t b = blockIdx.y;
  gemm_tn_core<true>(Q + b * 2048 * 1024, K + b * 2048 * 1024, S + b * 2048 * 2048,
                     1024, 1024, 2048, qb * 128, kb * 128, 32);
}

// PV: O[b] [2048,1024] f32 = P[b] @ V[b]; K-extent = (qb+1)*128 (causal)
__global__ __launch_bounds__(256) void pv_kernel(const ushort* __restrict__ P,
                                                 const ushort* __restrict__ Vt,
                                                 float* __restrict__ O) {
  int qb = blockIdx.x;
  size_t b = blockIdx.z;
  gemm_tn_core<false>(P + b * 2048 * 2048, Vt + b * 1024 * 2048, O + b * 2048 * 1024,
                      2048, 2048, 1024, qb * 128, blockIdx.y * 128, (qb + 1) * 4);
}

// ---------------- softmax (in-place on bf16 S) ----------------
__global__ __launch_bounds__(256) void softmax_kernel(ushort* __restrict__ S) {
  const int r = blockIdx.x;
  const int b = blockIdx.y;
  ushort* row = S + ((size_t)b * 2048 + r) * 2048;
  const int len = r + 1;
  const int padEnd = ((r >> 7) + 1) << 7;
  const int tid = threadIdx.x;
  const int base = tid * 8;
  const float scale = 0.03125f;  // 1/sqrt(1024)

  float v[8];
  float mymax = -1e30f;
  if (base < len) {
    short8 s = *(const short8*)(row + base);
#pragma unroll
    for (int j = 0; j < 8; ++j) {
      float f = (base + j < len) ? bf2f((ushort)s[j]) : -1e30f;
      v[j] = f;
      mymax = fmaxf(mymax, f);
    }
  } else {
#pragma unroll
    for (int j = 0; j < 8; ++j) v[j] = -1e30f;
  }

  __shared__ float redm[4], reds[4];
  const int wave = tid >> 6, lane = tid & 63;
#pragma unroll
  for (int off = 32; off > 0; off >>= 1) mymax = fmaxf(mymax, __shfl_xor(mymax, off, 64));
  if (lane == 0) redm[wave] = mymax;
  __syncthreads();
  float m = fmaxf(fmaxf(redm[0], redm[1]), fmaxf(redm[2], redm[3])) * scale;

  float p[8];
  float mysum = 0.f;
#pragma unroll
  for (int j = 0; j < 8; ++j) {
    float e = (base + j < len) ? __expf(v[j] * scale - m) : 0.f;
    p[j] = e;
    mysum += e;
  }
#pragma unroll
  for (int off = 32; off > 0; off >>= 1) mysum += __shfl_xor(mysum, off, 64);
  if (lane == 0) reds[wave] = mysum;
  __syncthreads();
  float inv = 1.f / (reds[0] + reds[1] + reds[2] + reds[3]);

  if (base < padEnd) {
    short8 o;
#pragma unroll
    for (int j = 0; j < 8; ++j) o[j] = (short)f2bf(p[j] * inv);
    *(short8*)(row + base) = o;
  }
}

// ---------------- launch ----------------

extern "C" void kernel_launch(void* const* d_in, const int* in_sizes, int n_in,
                              void* d_out, int out_size, void* d_ws, size_t ws_size,
                              hipStream_t stream) {
  const float* x  = (const float*)d_in[0];
  const float* Wq = (const float*)d_in[1];
  const float* Wk = (const float*)d_in[2];
  const float* Wv = (const float*)d_in[3];
  float* out = (float*)d_out;

  ushort* Xb  = (ushort*)d_ws;                        // 8192*1024
  ushort* Wt  = Xb + (size_t)8192 * 1024;             // 3*1024*1024 (= [3072][1024])
  ushort* QKV = Wt + (size_t)3 * 1024 * 1024;         // 3*8192*1024
  ushort* Vt  = QKV + (size_t)3 * 8192 * 1024;        // 4*1024*2048
  ushort* S   = Vt + (size_t)4 * 1024 * 2048;         // 4*2048*2048

  const ushort* Qp = QKV;
  const ushort* Kp = QKV + (size_t)8192 * 1024;
  const ushort* Vp = QKV + (size_t)2 * 8192 * 1024;

  hipLaunchKernelGGL(cvtx_kernel, dim3(4096), dim3(256), 0, stream, x, Xb);
  hipLaunchKernelGGL(wt_kernel, dim3(16, 16, 3), dim3(256), 0, stream, Wq, Wk, Wv, Wt);
  hipLaunchKernelGGL(qkv8_kernel, dim3(32, 12), dim3(512), 0, stream, Xb, Wt, QKV);
  hipLaunchKernelGGL(vt_kernel, dim3(32, 16, 4), dim3(256), 0, stream, Vp, Vt);
  hipLaunchKernelGGL(s_kernel, dim3(136, 4), dim3(256), 0, stream, Qp, Kp, S);
  hipLaunchKernelGGL(softmax_kernel, dim3(2048, 4), dim3(256), 0, stream, S);
  hipLaunchKernelGGL(pv_kernel, dim3(16, 8, 4), dim3(256), 0, stream, S, Vt, out);
}

// Round 3
// 187.332 us; speedup vs baseline: 1.0360x; 1.0073x over previous
//
#include <hip/hip_runtime.h>
#include <hip/hip_bf16.h>
#include <cstdint>

typedef __attribute__((ext_vector_type(8))) short short8;
typedef __attribute__((ext_vector_type(4))) short short4v;
typedef __attribute__((ext_vector_type(4))) float floatx4;
typedef unsigned short ushort;

__device__ __forceinline__ float bf2f(ushort u) {
  unsigned int x = ((unsigned int)u) << 16;
  return __builtin_bit_cast(float, x);
}
__device__ __forceinline__ ushort f2bf(float f) {
  unsigned int x = __builtin_bit_cast(unsigned int, f);
  x += 0x7fffu + ((x >> 16) & 1u);   // RNE
  return (ushort)(x >> 16);
}

__device__ __forceinline__ void gload_lds16(const void* g, void* l) {
  __builtin_amdgcn_global_load_lds(
      (const __attribute__((address_space(1))) void*)g,
      (__attribute__((address_space(3))) void*)l, 16, 0, 0);
}

// ---------------- converts ----------------

__global__ __launch_bounds__(256) void cvtx_kernel(const float* __restrict__ x,
                                                   ushort* __restrict__ xb) {
  int i = blockIdx.x * 256 + threadIdx.x;
  const float4* xf = (const float4*)x;
  float4 a = xf[i * 2], b = xf[i * 2 + 1];
  short8 o;
  o[0] = (short)f2bf(a.x); o[1] = (short)f2bf(a.y);
  o[2] = (short)f2bf(a.z); o[3] = (short)f2bf(a.w);
  o[4] = (short)f2bf(b.x); o[5] = (short)f2bf(b.y);
  o[6] = (short)f2bf(b.z); o[7] = (short)f2bf(b.w);
  ((short8*)xb)[i] = o;
}

// W [1024(d_in)][1024(d_out)] f32 -> Wt [d_out][d_in] bf16 (transposed)
__global__ __launch_bounds__(256) void wt_kernel(const float* __restrict__ Wq,
                                                 const float* __restrict__ Wk,
                                                 const float* __restrict__ Wv,
                                                 ushort* __restrict__ Wt) {
  int z = blockIdx.z;
  const float* W = z == 0 ? Wq : (z == 1 ? Wk : Wv);
  ushort* O = Wt + (size_t)z * 1024 * 1024;
  __shared__ float tile[64][65];
  int c0 = blockIdx.x * 64;
  int r0 = blockIdx.y * 64;
  int tid = threadIdx.x;
#pragma unroll
  for (int i = 0; i < 4; ++i) {
    int c = tid + i * 256; int rr = c >> 4, q = c & 15;
    float4 v = *(const float4*)&W[(size_t)(r0 + rr) * 1024 + c0 + q * 4];
    tile[rr][q * 4 + 0] = v.x; tile[rr][q * 4 + 1] = v.y;
    tile[rr][q * 4 + 2] = v.z; tile[rr][q * 4 + 3] = v.w;
  }
  __syncthreads();
#pragma unroll
  for (int i = 0; i < 2; ++i) {
    int c = tid + i * 256; int oc = c >> 3, q = c & 7;
    short8 o;
#pragma unroll
    for (int j = 0; j < 8; ++j) o[j] = (short)f2bf(tile[q * 8 + j][oc]);
    *(short8*)&O[(size_t)(c0 + oc) * 1024 + r0 + q * 8] = o;
  }
}

// ---------------- QKV: 128x256 tile, 4 waves, BK=32, 3-buffer 8-phase ----------------
// C[8192,3072] = X[8192,1024] * WtAll[3072,1024]^T.
// z=0 -> Q, z=1 -> K (row-major bf16), z=2 -> stored TRANSPOSED into Vt[b][e][t].
// 768 blocks, 72 KiB LDS -> 2 blocks/CU. Per wave: 128x64 out, 16 MFMA/phase.

__global__ __launch_bounds__(256, 2) void qkv2_kernel(const ushort* __restrict__ A,
                                                      const ushort* __restrict__ Bm,
                                                      ushort* __restrict__ Qo,
                                                      ushort* __restrict__ Ko,
                                                      ushort* __restrict__ Vt) {
  __shared__ __align__(16) ushort ldsA[3][128 * 32];   // 24 KiB
  __shared__ __align__(16) ushort ldsB[3][256 * 32];   // 48 KiB

  const int tid = threadIdx.x;
  const int lane = tid & 63;
  const int wave = tid >> 6;        // 0..3 -> 64-col slice
  const int r15 = lane & 15;
  const int kg = lane >> 4;         // 0..3

  // XCD-bijective swizzle: nwg = 768, 768 % 8 == 0, chunk = 96
  int orig = blockIdx.y * 64 + blockIdx.x;
  int swz = (orig & 7) * 96 + (orig >> 3);
  int bx = swz / 12;                // m-tile (0..63)
  int by = swz % 12;                // n-tile (0..11)
  const int m0 = bx * 128;
  const int n0 = by * 256;

  const ushort* Ag = A + (size_t)m0 * 1024;
  const ushort* Bg = Bm + (size_t)n0 * 1024;

  const int NKT = 32;  // 1024 / 32

  floatx4 acc[8][4] = {};

  // one stage = tile kt: A 128x32 (2 insts/thread) + B 256x32 (4 insts/thread)
  auto stage = [&](int kt, int slot) {
    int k0 = kt * 32;
#pragma unroll
    for (int i = 0; i < 2; ++i) {
      int c = tid + i * 256;
      int d = c * 16;
      int L = d ^ (((d >> 7) & 3) << 4);
      gload_lds16(Ag + (size_t)(L >> 6) * 1024 + k0 + ((L & 63) >> 1),
                  &ldsA[slot][c * 8]);
    }
#pragma unroll
    for (int i = 0; i < 4; ++i) {
      int c = tid + i * 256;
      int d = c * 16;
      int L = d ^ (((d >> 7) & 3) << 4);
      gload_lds16(Bg + (size_t)(L >> 6) * 1024 + k0 + ((L & 63) >> 1),
                  &ldsB[slot][c * 8]);
    }
  };

  auto ldA = [&](int slot, int m) -> short8 {
    int row = m * 16 + r15;
    int P = (row * 64 + kg * 16) ^ (((row >> 1) & 3) << 4);
    return *(const short8*)((const char*)&ldsA[slot][0] + P);
  };
  auto ldB = [&](int slot, int n) -> short8 {
    int row = wave * 64 + n * 16 + r15;
    int P = (row * 64 + kg * 16) ^ (((row >> 1) & 3) << 4);
    return *(const short8*)((const char*)&ldsB[slot][0] + P);
  };

  stage(0, 0);
  stage(1, 1);
  asm volatile("s_waitcnt vmcnt(6)" ::: "memory");  // stage 0 landed
  __builtin_amdgcn_s_barrier();

  int cur = 0;
  for (int kt = 0; kt < NKT; ++kt) {
    // ---- phase q0: B frags + A frags m0..3, issue stage(kt+2) ----
    short8 bfrag[4], afrag[4];
#pragma unroll
    for (int n = 0; n < 4; ++n) bfrag[n] = ldB(cur, n);
#pragma unroll
    for (int m = 0; m < 4; ++m) afrag[m] = ldA(cur, m);
    if (kt + 2 < NKT) {
      int slot = cur + 2; if (slot >= 3) slot -= 3;
      stage(kt + 2, slot);
    }
    __builtin_amdgcn_s_barrier();
    asm volatile("s_waitcnt lgkmcnt(0)" ::: "memory");
    __builtin_amdgcn_sched_barrier(0);
    __builtin_amdgcn_s_setprio(1);
#pragma unroll
    for (int m = 0; m < 4; ++m)
#pragma unroll
      for (int n = 0; n < 4; ++n)
        acc[m][n] = __builtin_amdgcn_mfma_f32_16x16x32_bf16(afrag[m], bfrag[n], acc[m][n], 0, 0, 0);
    __builtin_amdgcn_s_setprio(0);
    __builtin_amdgcn_s_barrier();

    // ---- phase q1: A frags m4..7 ----
#pragma unroll
    for (int m = 0; m < 4; ++m) afrag[m] = ldA(cur, m + 4);
    if (kt >= NKT - 3) {
      asm volatile("s_waitcnt vmcnt(0)" ::: "memory");  // epilogue drain
    } else {
      asm volatile("s_waitcnt vmcnt(6)" ::: "memory");  // next tile landed, 1 in flight
    }
    __builtin_amdgcn_s_barrier();
    asm volatile("s_waitcnt lgkmcnt(0)" ::: "memory");
    __builtin_amdgcn_sched_barrier(0);
    __builtin_amdgcn_s_setprio(1);
#pragma unroll
    for (int m = 0; m < 4; ++m)
#pragma unroll
      for (int n = 0; n < 4; ++n)
        acc[m + 4][n] = __builtin_amdgcn_mfma_f32_16x16x32_bf16(afrag[m], bfrag[n], acc[m + 4][n], 0, 0, 0);
    __builtin_amdgcn_s_setprio(0);
    __builtin_amdgcn_s_barrier();

    ++cur; if (cur >= 3) cur = 0;
  }

  // ---- epilogue ----
  const int z = n0 >> 10;
  const int rq = kg * 4;
  if (z < 2) {
    ushort* Cz = z == 0 ? Qo : Ko;
    const int cb = n0 & 1023;
#pragma unroll
    for (int m = 0; m < 8; ++m) {
#pragma unroll
      for (int n = 0; n < 4; ++n) {
        int gc = cb + wave * 64 + n * 16 + r15;
#pragma unroll
        for (int r = 0; r < 4; ++r) {
          int gr = m0 + m * 16 + rq + r;
          Cz[(size_t)gr * 1024 + gc] = f2bf(acc[m][n][r]);
        }
      }
    }
  } else {
    // V: store transposed -> Vt[b][e][t], 4 consecutive t per lane = 8B store
#pragma unroll
    for (int m = 0; m < 8; ++m) {
      int gr = m0 + m * 16 + rq;       // 4-aligned token row
      int b = gr >> 11;
      int t = gr & 2047;
      ushort* Vb = Vt + (size_t)b * 1024 * 2048;
#pragma unroll
      for (int n = 0; n < 4; ++n) {
        int e = (n0 - 2048) + wave * 64 + n * 16 + r15;
        short4v o;
#pragma unroll
        for (int r = 0; r < 4; ++r) o[r] = (short)f2bf(acc[m][n][r]);
        *(short4v*)&Vb[(size_t)e * 2048 + t] = o;
      }
    }
  }
}

// ---------------- TN GEMM core (m97 structure) for S and PV ----------------

template <bool OUT_BF16>
__device__ __forceinline__ void gemm_tn_core(const ushort* __restrict__ A,
                                             const ushort* __restrict__ B,
                                             void* __restrict__ C,
                                             int lda, int ldb, int ldc,
                                             int m0, int n0, int kTiles) {
  __shared__ __align__(16) ushort Asm[2][128 * 32];
  __shared__ __align__(16) ushort Bsm[2][128 * 32];
  const int tid = threadIdx.x;
  const int lane = tid & 63;
  const int wave = tid >> 6;
  const int wrow = (wave >> 1) * 64;
  const int wcol = (wave & 1) * 64;
  const int r15 = lane & 15;
  const int kg = (lane >> 4) * 8;

  floatx4 acc[4][4] = {};

  const ushort* Ag = A + (size_t)m0 * lda;
  const ushort* Bg = B + (size_t)n0 * ldb;

  auto stage = [&](int buf, int kt) {
    int k0 = kt * 32;
#pragma unroll
    for (int i = 0; i < 2; ++i) {
      int c = tid + i * 256;
      gload_lds16(Ag + (size_t)(c >> 2) * lda + k0 + (c & 3) * 8, &Asm[buf][c * 8]);
    }
#pragma unroll
    for (int i = 0; i < 2; ++i) {
      int c = tid + i * 256;
      gload_lds16(Bg + (size_t)(c >> 2) * ldb + k0 + (c & 3) * 8, &Bsm[buf][c * 8]);
    }
  };

  stage(0, 0);
  for (int kt = 0; kt < kTiles; ++kt) {
    int cur = kt & 1;
    __syncthreads();
    if (kt + 1 < kTiles) stage(cur ^ 1, kt + 1);
    const ushort* As = Asm[cur];
    const ushort* Bs = Bsm[cur];
    short8 af[4], bfr[4];
#pragma unroll
    for (int m = 0; m < 4; ++m)
      af[m] = *(const short8*)&As[(wrow + m * 16 + r15) * 32 + kg];
#pragma unroll
    for (int n = 0; n < 4; ++n)
      bfr[n] = *(const short8*)&Bs[(wcol + n * 16 + r15) * 32 + kg];
#pragma unroll
    for (int m = 0; m < 4; ++m)
#pragma unroll
      for (int n = 0; n < 4; ++n)
        acc[m][n] = __builtin_amdgcn_mfma_f32_16x16x32_bf16(af[m], bfr[n], acc[m][n], 0, 0, 0);
  }

  const int rq = (lane >> 4) * 4;
#pragma unroll
  for (int m = 0; m < 4; ++m) {
#pragma unroll
    for (int n = 0; n < 4; ++n) {
      int gc = n0 + wcol + n * 16 + r15;
#pragma unroll
      for (int r = 0; r < 4; ++r) {
        int gr = m0 + wrow + m * 16 + rq + r;
        if (OUT_BF16)
          ((ushort*)C)[(size_t)gr * ldc + gc] = f2bf(acc[m][n][r]);
        else
          ((float*)C)[(size_t)gr * ldc + gc] = acc[m][n][r];
      }
    }
  }
}

// S: triangular grid over (qb, kb<=qb)
__global__ __launch_bounds__(256) void s_kernel(const ushort* __restrict__ Q,
                                                const ushort* __restrict__ K,
                                                ushort* __restrict__ S) {
  int t = blockIdx.x;
  int qb = (int)((sqrtf(8.f * (float)t + 1.f) - 1.f) * 0.5f);
  while ((qb + 1) * (qb + 2) / 2 <= t) ++qb;
  while (qb * (qb + 1) / 2 > t) --qb;
  int kb = t - qb * (qb + 1) / 2;
  size_t b = blockIdx.y;
  gemm_tn_core<true>(Q + b * 2048 * 1024, K + b * 2048 * 1024, S + b * 2048 * 2048,
                     1024, 1024, 2048, qb * 128, kb * 128, 32);
}

// PV: O[b] [2048,1024] f32 = P[b] @ V[b]; K-extent = (qb+1)*128 (causal)
__global__ __launch_bounds__(256) void pv_kernel(const ushort* __restrict__ P,
                                                 const ushort* __restrict__ Vt,
                                                 float* __restrict__ O) {
  int qb = blockIdx.x;
  size_t b = blockIdx.z;
  gemm_tn_core<false>(P + b * 2048 * 2048, Vt + b * 1024 * 2048, O + b * 2048 * 1024,
                      2048, 2048, 1024, qb * 128, blockIdx.y * 128, (qb + 1) * 4);
}

// ---------------- softmax (in-place on bf16 S) ----------------
__global__ __launch_bounds__(256) void softmax_kernel(ushort* __restrict__ S) {
  const int r = blockIdx.x;
  const int b = blockIdx.y;
  ushort* row = S + ((size_t)b * 2048 + r) * 2048;
  const int len = r + 1;
  const int padEnd = ((r >> 7) + 1) << 7;
  const int tid = threadIdx.x;
  const int base = tid * 8;
  const float scale = 0.03125f;  // 1/sqrt(1024)

  float v[8];
  float mymax = -1e30f;
  if (base < len) {
    short8 s = *(const short8*)(row + base);
#pragma unroll
    for (int j = 0; j < 8; ++j) {
      float f = (base + j < len) ? bf2f((ushort)s[j]) : -1e30f;
      v[j] = f;
      mymax = fmaxf(mymax, f);
    }
  } else {
#pragma unroll
    for (int j = 0; j < 8; ++j) v[j] = -1e30f;
  }

  __shared__ float redm[4], reds[4];
  const int wave = tid >> 6, lane = tid & 63;
#pragma unroll
  for (int off = 32; off > 0; off >>= 1) mymax = fmaxf(mymax, __shfl_xor(mymax, off, 64));
  if (lane == 0) redm[wave] = mymax;
  __syncthreads();
  float m = fmaxf(fmaxf(redm[0], redm[1]), fmaxf(redm[2], redm[3])) * scale;

  float p[8];
  float mysum = 0.f;
#pragma unroll
  for (int j = 0; j < 8; ++j) {
    float e = (base + j < len) ? __expf(v[j] * scale - m) : 0.f;
    p[j] = e;
    mysum += e;
  }
#pragma unroll
  for (int off = 32; off > 0; off >>= 1) mysum += __shfl_xor(mysum, off, 64);
  if (lane == 0) reds[wave] = mysum;
  __syncthreads();
  float inv = 1.f / (reds[0] + reds[1] + reds[2] + reds[3]);

  if (base < padEnd) {
    short8 o;
#pragma unroll
    for (int j = 0; j < 8; ++j) o[j] = (short)f2bf(p[j] * inv);
    *(short8*)(row + base) = o;
  }
}

// ---------------- launch ----------------

extern "C" void kernel_launch(void* const* d_in, const int* in_sizes, int n_in,
                              void* d_out, int out_size, void* d_ws, size_t ws_size,
                              hipStream_t stream) {
  const float* x  = (const float*)d_in[0];
  const float* Wq = (const float*)d_in[1];
  const float* Wk = (const float*)d_in[2];
  const float* Wv = (const float*)d_in[3];
  float* out = (float*)d_out;

  ushort* Xb  = (ushort*)d_ws;                        // 8192*1024
  ushort* Wt  = Xb + (size_t)8192 * 1024;             // 3*1024*1024 (= [3072][1024])
  ushort* QK  = Wt + (size_t)3 * 1024 * 1024;         // 2*8192*1024 (Q then K)
  ushort* Vt  = QK + (size_t)2 * 8192 * 1024;         // 4*1024*2048
  ushort* S   = Vt + (size_t)4 * 1024 * 2048;         // 4*2048*2048

  ushort* Qp = QK;
  ushort* Kp = QK + (size_t)8192 * 1024;

  hipLaunchKernelGGL(cvtx_kernel, dim3(4096), dim3(256), 0, stream, x, Xb);
  hipLaunchKernelGGL(wt_kernel, dim3(16, 16, 3), dim3(256), 0, stream, Wq, Wk, Wv, Wt);
  hipLaunchKernelGGL(qkv2_kernel, dim3(64, 12), dim3(256), 0, stream, Xb, Wt, Qp, Kp, Vt);
  hipLaunchKernelGGL(s_kernel, dim3(136, 4), dim3(256), 0, stream, Qp, Kp, S);
  hipLaunchKernelGGL(softmax_kernel, dim3(2048, 4), dim3(256), 0, stream, S);
  hipLaunchKernelGGL(pv_kernel, dim3(16, 8, 4), dim3(256), 0, stream, S, Vt, out);
}

// Round 4
// 185.292 us; speedup vs baseline: 1.0474x; 1.0110x over previous
//
#include <hip/hip_runtime.h>
#include <hip/hip_bf16.h>
#include <cstdint>

typedef __attribute__((ext_vector_type(8))) short short8;
typedef __attribute__((ext_vector_type(4))) short short4v;
typedef __attribute__((ext_vector_type(4))) float floatx4;
typedef unsigned short ushort;

__device__ __forceinline__ float bf2f(ushort u) {
  unsigned int x = ((unsigned int)u) << 16;
  return __builtin_bit_cast(float, x);
}
__device__ __forceinline__ ushort f2bf(float f) {
  unsigned int x = __builtin_bit_cast(unsigned int, f);
  x += 0x7fffu + ((x >> 16) & 1u);   // RNE
  return (ushort)(x >> 16);
}

__device__ __forceinline__ void gload_lds16(const void* g, void* l) {
  __builtin_amdgcn_global_load_lds(
      (const __attribute__((address_space(1))) void*)g,
      (__attribute__((address_space(3))) void*)l, 16, 0, 0);
}

// ---------------- converts ----------------

__global__ __launch_bounds__(256) void cvtx_kernel(const float* __restrict__ x,
                                                   ushort* __restrict__ xb) {
  int i = blockIdx.x * 256 + threadIdx.x;
  const float4* xf = (const float4*)x;
  float4 a = xf[i * 2], b = xf[i * 2 + 1];
  short8 o;
  o[0] = (short)f2bf(a.x); o[1] = (short)f2bf(a.y);
  o[2] = (short)f2bf(a.z); o[3] = (short)f2bf(a.w);
  o[4] = (short)f2bf(b.x); o[5] = (short)f2bf(b.y);
  o[6] = (short)f2bf(b.z); o[7] = (short)f2bf(b.w);
  ((short8*)xb)[i] = o;
}

// W [1024(d_in)][1024(d_out)] f32 -> Wt [d_out][d_in] bf16 (transposed)
__global__ __launch_bounds__(256) void wt_kernel(const float* __restrict__ Wq,
                                                 const float* __restrict__ Wk,
                                                 const float* __restrict__ Wv,
                                                 ushort* __restrict__ Wt) {
  int z = blockIdx.z;
  const float* W = z == 0 ? Wq : (z == 1 ? Wk : Wv);
  ushort* O = Wt + (size_t)z * 1024 * 1024;
  __shared__ float tile[64][65];
  int c0 = blockIdx.x * 64;
  int r0 = blockIdx.y * 64;
  int tid = threadIdx.x;
#pragma unroll
  for (int i = 0; i < 4; ++i) {
    int c = tid + i * 256; int rr = c >> 4, q = c & 15;
    float4 v = *(const float4*)&W[(size_t)(r0 + rr) * 1024 + c0 + q * 4];
    tile[rr][q * 4 + 0] = v.x; tile[rr][q * 4 + 1] = v.y;
    tile[rr][q * 4 + 2] = v.z; tile[rr][q * 4 + 3] = v.w;
  }
  __syncthreads();
#pragma unroll
  for (int i = 0; i < 2; ++i) {
    int c = tid + i * 256; int oc = c >> 3, q = c & 7;
    short8 o;
#pragma unroll
    for (int j = 0; j < 8; ++j) o[j] = (short)f2bf(tile[q * 8 + j][oc]);
    *(short8*)&O[(size_t)(c0 + oc) * 1024 + r0 + q * 8] = o;
  }
}

// ---------------- QKV: 256x256, 8 waves, BK=64 (2x K-half 32), m201 schedule ----------------
// C[8192,3072] = X[8192,1024] * WtAll[3072,1024]^T.
// z=0 -> Q, z=1 -> K (row-major), z=2 -> stored TRANSPOSED into Vt[b][e][t].
// Stage stream s: j = s>>2 (K-tile), h = s&3: 0=B-kh0, 1=A-kh0, 2=B-kh1, 3=A-kh1.
// Phase q of kt stages s = 7 + kt*4 + q; hazard-safe by construction:
//   q0 stages h3 of kt+1 (other buf, fully consumed); q1 stages B-kh0 of kt+2
//   (last read q0); q2 stages A-kh0 (read q1); q3 stages B-kh1 (read q2).
// vmcnt(6) at q3 only (next K-tile landed, 3 halves in flight).

__global__ __launch_bounds__(512, 2) void qkv8_kernel(const ushort* __restrict__ A,
                                                      const ushort* __restrict__ Bm,
                                                      ushort* __restrict__ Qo,
                                                      ushort* __restrict__ Ko,
                                                      ushort* __restrict__ Vt) {
  // [buf][mat 0=A,1=B][kh][256 rows * 32 k]
  __shared__ __align__(16) ushort lds[2][2][2][8192];

  const int tid = threadIdx.x;
  const int lane = tid & 63;
  const int wave = tid >> 6;
  const int wm = wave >> 2;   // 0..1 -> 128-row half
  const int wn = wave & 3;    // 0..3 -> 64-col slice
  const int r15 = lane & 15;
  const int kg = lane >> 4;   // 0..3

  // XCD-bijective swizzle (nwg = 384, 384 % 8 == 0)
  int orig = blockIdx.y * 32 + blockIdx.x;
  int swz = (orig & 7) * 48 + (orig >> 3);
  int by = swz % 12;
  int bx = swz / 12;
  const int m0 = bx * 256;
  const int n0 = by * 256;

  const ushort* Ag = A + (size_t)m0 * 1024;
  const ushort* Bg = Bm + (size_t)n0 * 1024;

  const int NKT = 16;  // 1024 / 64

  floatx4 acc[8][4] = {};

  auto stage = [&](int j, int h) {
    const int isA = h & 1;
    const int kh = h >> 1;
    ushort* dst = &lds[j & 1][isA ? 0 : 1][kh][0];
    const ushort* src = isA ? Ag : Bg;
    const int kbase = j * 64 + kh * 32;
#pragma unroll
    for (int i = 0; i < 2; ++i) {
      int t = tid + i * 512;
      int d = t * 16;                       // linear LDS dest byte
      int L = d ^ (((d >> 7) & 3) << 4);    // inverse-swizzled logical byte
      gload_lds16(src + (size_t)(L >> 6) * 1024 + kbase + ((L & 63) >> 1),
                  dst + t * 8);
    }
  };

  auto ldA = [&](int buf, int kh, int m) -> short8 {
    int row = wm * 128 + m * 16 + r15;
    int P = (row * 64 + kg * 16) ^ (((row >> 1) & 3) << 4);
    return *(const short8*)((const char*)&lds[buf][0][kh][0] + P);
  };
  auto ldB = [&](int buf, int kh, int n) -> short8 {
    int row = wn * 64 + n * 16 + r15;
    int P = (row * 64 + kg * 16) ^ (((row >> 1) & 3) << 4);
    return *(const short8*)((const char*)&lds[buf][1][kh][0] + P);
  };

  // prologue: stream s=0..6 (K-tile 0 complete + 3 halves of K-tile 1)
#pragma unroll
  for (int s = 0; s < 7; ++s) stage(s >> 2, s & 3);
  asm volatile("s_waitcnt vmcnt(6)" ::: "memory");  // K-tile 0 landed
  __builtin_amdgcn_s_barrier();

#define PHASE_MFMA(MS)                                                              \
  __builtin_amdgcn_s_barrier();                                                     \
  asm volatile("s_waitcnt lgkmcnt(0)" ::: "memory");                                \
  __builtin_amdgcn_sched_barrier(0);                                                \
  __builtin_amdgcn_s_setprio(1);                                                    \
  _Pragma("unroll") for (int m = 0; m < 4; ++m)                                     \
  _Pragma("unroll") for (int n = 0; n < 4; ++n)                                     \
      acc[(MS) + m][n] = __builtin_amdgcn_mfma_f32_16x16x32_bf16(                   \
          afrag[m], bfrag[n], acc[(MS) + m][n], 0, 0, 0);                           \
  __builtin_amdgcn_s_setprio(0);                                                    \
  __builtin_amdgcn_s_barrier();

  short8 bfrag[4], afrag[4];
  for (int kt = 0; kt < NKT; ++kt) {
    const int buf = kt & 1;
    const int sb = 7 + kt * 4;

    // ---- q0: B-kh0 frags + A-kh0 m0-3 ----
#pragma unroll
    for (int n = 0; n < 4; ++n) bfrag[n] = ldB(buf, 0, n);
#pragma unroll
    for (int m = 0; m < 4; ++m) afrag[m] = ldA(buf, 0, m);
    if (((sb + 0) >> 2) < NKT) stage((sb + 0) >> 2, (sb + 0) & 3);
    PHASE_MFMA(0)

    // ---- q1: A-kh0 m4-7 ----
#pragma unroll
    for (int m = 0; m < 4; ++m) afrag[m] = ldA(buf, 0, m + 4);
    if (((sb + 1) >> 2) < NKT) stage((sb + 1) >> 2, (sb + 1) & 3);
    PHASE_MFMA(4)

    // ---- q2: B-kh1 frags + A-kh1 m0-3 ----
#pragma unroll
    for (int n = 0; n < 4; ++n) bfrag[n] = ldB(buf, 1, n);
#pragma unroll
    for (int m = 0; m < 4; ++m) afrag[m] = ldA(buf, 1, m);
    if (((sb + 2) >> 2) < NKT) stage((sb + 2) >> 2, (sb + 2) & 3);
    PHASE_MFMA(0)

    // ---- q3: A-kh1 m4-7, counted vmcnt once per K-tile ----
#pragma unroll
    for (int m = 0; m < 4; ++m) afrag[m] = ldA(buf, 1, m + 4);
    if (((sb + 3) >> 2) < NKT) stage((sb + 3) >> 2, (sb + 3) & 3);
    if (kt < NKT - 2) {
      asm volatile("s_waitcnt vmcnt(6)" ::: "memory");   // kt+1 landed, 3 halves in flight
    } else if (kt == NKT - 2) {
      asm volatile("s_waitcnt vmcnt(0)" ::: "memory");   // tail drain: kt+1 complete
    }
    PHASE_MFMA(4)
  }
#undef PHASE_MFMA

  // ---- epilogue: z-split store ----
  const int z = n0 >> 10;
  const int rq = kg * 4;
  if (z < 2) {
    ushort* Cz = z == 0 ? Qo : Ko;
    const int cb = n0 & 1023;
#pragma unroll
    for (int m = 0; m < 8; ++m) {
#pragma unroll
      for (int n = 0; n < 4; ++n) {
        int gc = cb + wn * 64 + n * 16 + r15;
#pragma unroll
        for (int r = 0; r < 4; ++r) {
          int gr = m0 + wm * 128 + m * 16 + rq + r;
          Cz[(size_t)gr * 1024 + gc] = f2bf(acc[m][n][r]);
        }
      }
    }
  } else {
    // V: store transposed -> Vt[b][e][t], 4 consecutive t per lane = 8B store
#pragma unroll
    for (int m = 0; m < 8; ++m) {
      int gr = m0 + wm * 128 + m * 16 + rq;   // 4-aligned token row
      int b = gr >> 11;
      int t = gr & 2047;
      ushort* Vb = Vt + (size_t)b * 1024 * 2048;
#pragma unroll
      for (int n = 0; n < 4; ++n) {
        int e = (n0 - 2048) + wn * 64 + n * 16 + r15;
        short4v o;
#pragma unroll
        for (int r = 0; r < 4; ++r) o[r] = (short)f2bf(acc[m][n][r]);
        *(short4v*)&Vb[(size_t)e * 2048 + t] = o;
      }
    }
  }
}

// ---------------- TN GEMM core (m97 structure) for S and PV ----------------

template <bool OUT_BF16>
__device__ __forceinline__ void gemm_tn_core(const ushort* __restrict__ A,
                                             const ushort* __restrict__ B,
                                             void* __restrict__ C,
                                             int lda, int ldb, int ldc,
                                             int m0, int n0, int kTiles) {
  __shared__ __align__(16) ushort Asm[2][128 * 32];
  __shared__ __align__(16) ushort Bsm[2][128 * 32];
  const int tid = threadIdx.x;
  const int lane = tid & 63;
  const int wave = tid >> 6;
  const int wrow = (wave >> 1) * 64;
  const int wcol = (wave & 1) * 64;
  const int r15 = lane & 15;
  const int kg = (lane >> 4) * 8;

  floatx4 acc[4][4] = {};

  const ushort* Ag = A + (size_t)m0 * lda;
  const ushort* Bg = B + (size_t)n0 * ldb;

  auto stage = [&](int buf, int kt) {
    int k0 = kt * 32;
#pragma unroll
    for (int i = 0; i < 2; ++i) {
      int c = tid + i * 256;
      gload_lds16(Ag + (size_t)(c >> 2) * lda + k0 + (c & 3) * 8, &Asm[buf][c * 8]);
    }
#pragma unroll
    for (int i = 0; i < 2; ++i) {
      int c = tid + i * 256;
      gload_lds16(Bg + (size_t)(c >> 2) * ldb + k0 + (c & 3) * 8, &Bsm[buf][c * 8]);
    }
  };

  stage(0, 0);
  for (int kt = 0; kt < kTiles; ++kt) {
    int cur = kt & 1;
    __syncthreads();
    if (kt + 1 < kTiles) stage(cur ^ 1, kt + 1);
    const ushort* As = Asm[cur];
    const ushort* Bs = Bsm[cur];
    short8 af[4], bfr[4];
#pragma unroll
    for (int m = 0; m < 4; ++m)
      af[m] = *(const short8*)&As[(wrow + m * 16 + r15) * 32 + kg];
#pragma unroll
    for (int n = 0; n < 4; ++n)
      bfr[n] = *(const short8*)&Bs[(wcol + n * 16 + r15) * 32 + kg];
#pragma unroll
    for (int m = 0; m < 4; ++m)
#pragma unroll
      for (int n = 0; n < 4; ++n)
        acc[m][n] = __builtin_amdgcn_mfma_f32_16x16x32_bf16(af[m], bfr[n], acc[m][n], 0, 0, 0);
  }

  const int rq = (lane >> 4) * 4;
#pragma unroll
  for (int m = 0; m < 4; ++m) {
#pragma unroll
    for (int n = 0; n < 4; ++n) {
      int gc = n0 + wcol + n * 16 + r15;
#pragma unroll
      for (int r = 0; r < 4; ++r) {
        int gr = m0 + wrow + m * 16 + rq + r;
        if (OUT_BF16)
          ((ushort*)C)[(size_t)gr * ldc + gc] = f2bf(acc[m][n][r]);
        else
          ((float*)C)[(size_t)gr * ldc + gc] = acc[m][n][r];
      }
    }
  }
}

// S: triangular grid over (qb, kb<=qb)
__global__ __launch_bounds__(256) void s_kernel(const ushort* __restrict__ Q,
                                                const ushort* __restrict__ K,
                                                ushort* __restrict__ S) {
  int t = blockIdx.x;
  int qb = (int)((sqrtf(8.f * (float)t + 1.f) - 1.f) * 0.5f);
  while ((qb + 1) * (qb + 2) / 2 <= t) ++qb;
  while (qb * (qb + 1) / 2 > t) --qb;
  int kb = t - qb * (qb + 1) / 2;
  size_t b = blockIdx.y;
  gemm_tn_core<true>(Q + b * 2048 * 1024, K + b * 2048 * 1024, S + b * 2048 * 2048,
                     1024, 1024, 2048, qb * 128, kb * 128, 32);
}

// PV: O[b] [2048,1024] f32 = P[b] @ V[b]; K-extent = (qb+1)*128 (causal)
__global__ __launch_bounds__(256) void pv_kernel(const ushort* __restrict__ P,
                                                 const ushort* __restrict__ Vt,
                                                 float* __restrict__ O) {
  int qb = blockIdx.x;
  size_t b = blockIdx.z;
  gemm_tn_core<false>(P + b * 2048 * 2048, Vt + b * 1024 * 2048, O + b * 2048 * 1024,
                      2048, 2048, 1024, qb * 128, blockIdx.y * 128, (qb + 1) * 4);
}

// ---------------- softmax (in-place on bf16 S) ----------------
__global__ __launch_bounds__(256) void softmax_kernel(ushort* __restrict__ S) {
  const int r = blockIdx.x;
  const int b = blockIdx.y;
  ushort* row = S + ((size_t)b * 2048 + r) * 2048;
  const int len = r + 1;
  const int padEnd = ((r >> 7) + 1) << 7;
  const int tid = threadIdx.x;
  const int base = tid * 8;
  const float scale = 0.03125f;  // 1/sqrt(1024)

  float v[8];
  float mymax = -1e30f;
  if (base < len) {
    short8 s = *(const short8*)(row + base);
#pragma unroll
    for (int j = 0; j < 8; ++j) {
      float f = (base + j < len) ? bf2f((ushort)s[j]) : -1e30f;
      v[j] = f;
      mymax = fmaxf(mymax, f);
    }
  } else {
#pragma unroll
    for (int j = 0; j < 8; ++j) v[j] = -1e30f;
  }

  __shared__ float redm[4], reds[4];
  const int wave = tid >> 6, lane = tid & 63;
#pragma unroll
  for (int off = 32; off > 0; off >>= 1) mymax = fmaxf(mymax, __shfl_xor(mymax, off, 64));
  if (lane == 0) redm[wave] = mymax;
  __syncthreads();
  float m = fmaxf(fmaxf(redm[0], redm[1]), fmaxf(redm[2], redm[3])) * scale;

  float p[8];
  float mysum = 0.f;
#pragma unroll
  for (int j = 0; j < 8; ++j) {
    float e = (base + j < len) ? __expf(v[j] * scale - m) : 0.f;
    p[j] = e;
    mysum += e;
  }
#pragma unroll
  for (int off = 32; off > 0; off >>= 1) mysum += __shfl_xor(mysum, off, 64);
  if (lane == 0) reds[wave] = mysum;
  __syncthreads();
  float inv = 1.f / (reds[0] + reds[1] + reds[2] + reds[3]);

  if (base < padEnd) {
    short8 o;
#pragma unroll
    for (int j = 0; j < 8; ++j) o[j] = (short)f2bf(p[j] * inv);
    *(short8*)(row + base) = o;
  }
}

// ---------------- launch ----------------

extern "C" void kernel_launch(void* const* d_in, const int* in_sizes, int n_in,
                              void* d_out, int out_size, void* d_ws, size_t ws_size,
                              hipStream_t stream) {
  const float* x  = (const float*)d_in[0];
  const float* Wq = (const float*)d_in[1];
  const float* Wk = (const float*)d_in[2];
  const float* Wv = (const float*)d_in[3];
  float* out = (float*)d_out;

  ushort* Xb  = (ushort*)d_ws;                        // 8192*1024
  ushort* Wt  = Xb + (size_t)8192 * 1024;             // 3*1024*1024 (= [3072][1024])
  ushort* QK  = Wt + (size_t)3 * 1024 * 1024;         // 2*8192*1024 (Q then K)
  ushort* Vt  = QK + (size_t)2 * 8192 * 1024;         // 4*1024*2048
  ushort* S   = Vt + (size_t)4 * 1024 * 2048;         // 4*2048*2048

  ushort* Qp = QK;
  ushort* Kp = QK + (size_t)8192 * 1024;

  hipLaunchKernelGGL(cvtx_kernel, dim3(4096), dim3(256), 0, stream, x, Xb);
  hipLaunchKernelGGL(wt_kernel, dim3(16, 16, 3), dim3(256), 0, stream, Wq, Wk, Wv, Wt);
  hipLaunchKernelGGL(qkv8_kernel, dim3(32, 12), dim3(512), 0, stream, Xb, Wt, Qp, Kp, Vt);
  hipLaunchKernelGGL(s_kernel, dim3(136, 4), dim3(256), 0, stream, Qp, Kp, S);
  hipLaunchKernelGGL(softmax_kernel, dim3(2048, 4), dim3(256), 0, stream, S);
  hipLaunchKernelGGL(pv_kernel, dim3(16, 8, 4), dim3(256), 0, stream, S, Vt, out);
}